// Round 2
// baseline (184.275 us; speedup 1.0000x reference)
//
#include <hip/hip_runtime.h>
#include <hip/hip_bf16.h>

#define K 16
#define Bn 1024
#define Tn 512
#define PAD_ID 0
#define START_ID 14
#define STOP_ID 15
#define LN2 0.69314718055994530942f

typedef float f32x4 __attribute__((ext_vector_type(4)));
typedef short s16x4 __attribute__((ext_vector_type(4)));

static __device__ __forceinline__ s16x4 pack_bf16x4(float a, float b, float c, float d) {
    __hip_bfloat162 lo = __float22bfloat162_rn(float2{a, b});
    __hip_bfloat162 hi = __float22bfloat162_rn(float2{c, d});
    union { __hip_bfloat162 h2[2]; s16x4 v; } u;
    u.h2[0] = lo; u.h2[1] = hi;
    return u.v;
}

// ---------------------------------------------------------------------------
// K0: lengths per sequence (mask is a contiguous prefix) + zero the ws
// accumulator/counter. One wave per sequence.
// ---------------------------------------------------------------------------
__global__ __launch_bounds__(256) void crf_len_kernel(
    const float* __restrict__ mask, int* __restrict__ len,
    float* __restrict__ acc, unsigned int* __restrict__ cnt)
{
    if (blockIdx.x == 0 && threadIdx.x == 0) { *acc = 0.f; *cnt = 0u; }
    int wid  = (blockIdx.x * blockDim.x + threadIdx.x) >> 6;
    int lane = threadIdx.x & 63;
    const float* m = mask + (size_t)wid * Tn;
    float s = 0.f;
#pragma unroll
    for (int k = 0; k < 8; ++k) s += m[lane + 64 * k];
#pragma unroll
    for (int off = 32; off; off >>= 1) s += __shfl_xor(s, off, 64);
    if (lane == 0) len[wid] = (int)(s + 0.5f);
}

// ---------------------------------------------------------------------------
// K1: forward score, 16 sequences per wave, direct recurrence over T.
//   alpha_{t+1}[j][s] = exp(h[s][t][j]) * sum_i E[j][i] * alpha_t[i][s]
// mfma_f32_16x16x16_bf16: A[m=lane&15][k=4q+r] = E (loop-invariant),
// B[k=4q+r][n=lane&15] = alpha, C/D[row=4q+r][col=lane&15] -> feeds back as B.
// Per-column (=per-seq) power-of-2 rescale every 8 steps, computed at step 5,
// applied EXACTLY via 2^-e fold into pe[0] of the next sub-block; esum tracks
// applied scales only, so the per-lane freeze snapshot (Cfin/esumfin) is
// consistent. Frozen columns keep evolving junk (confined per-column).
// h prefetched 24 steps (3 sub-blocks) deep to cover ~900cy HBM latency.
// ---------------------------------------------------------------------------
__global__ __launch_bounds__(64) void crf_fwd_kernel(
    const float* __restrict__ h, const float* __restrict__ trans,
    const int* __restrict__ len, float* __restrict__ acc)
{
    int lane = threadIdx.x;
    int s = lane & 15, q = lane >> 4;
    int sabs = blockIdx.x * 16 + s;

    // E fragment (A-operand): E[m=lane&15][k=4q+r]; exp(-10000) -> 0 exactly
    float e0 = __expf(trans[s * K + 4 * q + 0]);
    float e1 = __expf(trans[s * K + 4 * q + 1]);
    float e2 = __expf(trans[s * K + 4 * q + 2]);
    float e3 = __expf(trans[s * K + 4 * q + 3]);
    s16x4 afrag = pack_bf16x4(e0, e1, e2, e3);
    float Estop[4];
#pragma unroll
    for (int r = 0; r < 4; ++r)
        Estop[r] = __expf(trans[STOP_ID * K + 4 * q + r]);

    int lenm1 = len[sabs] - 1;                 // len >= 1 guaranteed
    int mx = lenm1;
#pragma unroll
    for (int off = 1; off < 16; off <<= 1) mx = max(mx, __shfl_xor(mx, off, 16));
    int Tmax = mx + 1;

    // alpha0 = e_START (bf16 1.0 = 0x3F80)
    s16x4 bfrag;
#pragma unroll
    for (int r = 0; r < 4; ++r)
        ((short*)&bfrag)[r] = (4 * q + r == START_ID) ? (short)0x3F80 : (short)0;

    f32x4 Cfin = {0.f, 0.f, 0.f, 0.f};
    int esum = 0, esumfin = 0, pend = 0;

    const float* hp = h + ((size_t)sabs * Tn) * K + 4 * q;

    f32x4 nbA[8], nbB[8], nbC[8];
#pragma unroll
    for (int r = 0; r < 8; ++r) {
        int t0 = r > lenm1 ? lenm1 : r;
        int t1 = 8 + r  > lenm1 ? lenm1 : 8 + r;
        int t2 = 16 + r > lenm1 ? lenm1 : 16 + r;
        nbA[r] = *(const f32x4*)(hp + (size_t)t0 * K);
        nbB[r] = *(const f32x4*)(hp + (size_t)t1 * K);
        nbC[r] = *(const f32x4*)(hp + (size_t)t2 * K);
    }

    auto subblock = [&](f32x4 (&nb)[8], int tb) {
        esum += pend;
        float sc2 = __uint_as_float((unsigned)(127 - pend) << 23);  // exact 2^-pend
        f32x4 pe[8];
#pragma unroll
        for (int r = 0; r < 8; ++r)
#pragma unroll
            for (int c2 = 0; c2 < 4; ++c2)
                pe[r][c2] = __expf(nb[r][c2]);
#pragma unroll
        for (int c2 = 0; c2 < 4; ++c2) pe[0][c2] *= sc2;
        // prefetch 3 sub-blocks (24 steps) ahead; clamp keeps loads in-bounds
#pragma unroll
        for (int r = 0; r < 8; ++r) {
            int tt = tb + 24 + r; tt = tt > lenm1 ? lenm1 : tt;
            nb[r] = *(const f32x4*)(hp + (size_t)tt * K);
        }
#pragma unroll
        for (int r = 0; r < 8; ++r) {
            f32x4 C = __builtin_amdgcn_mfma_f32_16x16x16bf16_1k(
                afrag, bfrag, (f32x4){0.f, 0.f, 0.f, 0.f}, 0, 0, 0);
#pragma unroll
            for (int c2 = 0; c2 < 4; ++c2) C[c2] *= pe[r][c2];
            bool fz = (tb + r == lenm1);        // per-lane freeze snapshot
#pragma unroll
            for (int c2 = 0; c2 < 4; ++c2) Cfin[c2] = fz ? C[c2] : Cfin[c2];
            esumfin = fz ? esum : esumfin;
            if (r == 5) {                       // per-column max -> pending 2^e
                float m4 = fmaxf(fmaxf(C[0], C[1]), fmaxf(C[2], C[3]));
                m4 = fmaxf(m4, __shfl_xor(m4, 16, 64));
                m4 = fmaxf(m4, __shfl_xor(m4, 32, 64));
                int e = (int)(__float_as_uint(m4) >> 23) - 127;
                pend = e < -126 ? -126 : (e > 126 ? 126 : e);
            }
            bfrag = pack_bf16x4(C[0], C[1], C[2], C[3]);
        }
    };

    for (int t0 = 0; t0 < Tmax; t0 += 24) {
        subblock(nbA, t0);
        subblock(nbB, t0 + 8);
        subblock(nbC, t0 + 16);
    }

    // fwd_s = ln2*esumfin + log(sum_j alpha[j][s] * Estop[j])
    float part = Cfin[0] * Estop[0] + Cfin[1] * Estop[1]
               + Cfin[2] * Estop[2] + Cfin[3] * Estop[3];
    part += __shfl_xor(part, 16, 64);
    part += __shfl_xor(part, 32, 64);
    float fwd = (float)esumfin * LN2 + __logf(part);
    float v = (q == 0) ? fwd : 0.f;
#pragma unroll
    for (int off = 32; off; off >>= 1) v += __shfl_xor(v, off, 64);
    if (lane == 0) atomicAdd(acc, v);
}

// ---------------------------------------------------------------------------
// K2: gold score (one thread per (b,t)), subtracts into acc; last block
// publishes out = acc / B.
// ---------------------------------------------------------------------------
__global__ __launch_bounds__(256) void crf_gold_kernel(
    const float* __restrict__ h, const int* __restrict__ y,
    const float* __restrict__ mask, const float* __restrict__ trans,
    float* __restrict__ acc, unsigned int* __restrict__ cnt,
    float* __restrict__ out)
{
    int idx = blockIdx.x * blockDim.x + threadIdx.x;   // B*T threads
    int t = idx & (Tn - 1);
    float g = 0.f;
    if (mask[idx] > 0.5f) {
        int yt = y[idx];
        int yp = (t == 0) ? START_ID : y[idx - 1];
        g = h[(size_t)idx * K + yt] + trans[yt * K + yp];
        bool last = (t == Tn - 1) || (mask[idx + 1] <= 0.5f);
        if (last) g += trans[STOP_ID * K + yt];
    }
    float v = g;
#pragma unroll
    for (int off = 32; off; off >>= 1) v += __shfl_down(v, off, 64);
    __shared__ float red[4];
    if ((threadIdx.x & 63) == 0) red[threadIdx.x >> 6] = v;
    __syncthreads();
    if (threadIdx.x == 0) {
        float sblk = red[0] + red[1] + red[2] + red[3];
        atomicAdd(acc, -sblk);
        __threadfence();
        unsigned int old = atomicAdd(cnt, 1u);
        if (old == (unsigned)(Bn * Tn / 256 - 1)) {
            float total = atomicAdd(acc, 0.f);   // coherent read of final sum
            out[0] = total * (1.0f / Bn);
        }
    }
}

extern "C" void kernel_launch(void* const* d_in, const int* in_sizes, int n_in,
                              void* d_out, int out_size, void* d_ws, size_t ws_size,
                              hipStream_t stream)
{
    const float* h     = (const float*)d_in[0];
    const int*   y     = (const int*)d_in[1];
    const float* mask  = (const float*)d_in[2];
    const float* trans = (const float*)d_in[3];
    float* out = (float*)d_out;

    float*        acc = (float*)d_ws;
    unsigned int* cnt = (unsigned int*)d_ws + 1;
    int*          len = (int*)d_ws + 2;

    crf_len_kernel<<<Bn / 4, 256, 0, stream>>>(mask, len, acc, cnt);
    crf_fwd_kernel<<<Bn / 16, 64, 0, stream>>>(h, trans, len, acc);
    crf_gold_kernel<<<(Bn * Tn) / 256, 256, 0, stream>>>(h, y, mask, trans, acc, cnt, out);
}

// Round 3
// 138.430 us; speedup vs baseline: 1.3312x; 1.3312x over previous
//
#include <hip/hip_runtime.h>
#include <hip/hip_bf16.h>

#define K 16
#define Bn 1024
#define Tn 512
#define START_ID 14
#define STOP_ID 15
#define LN2 0.69314718055994530942f
#define NG (Bn / 16)   // 64 sequence-groups, 16 seqs per mfma column block

typedef float f32x4 __attribute__((ext_vector_type(4)));
typedef short s16x4 __attribute__((ext_vector_type(4)));

static __device__ __forceinline__ s16x4 pack_bf16x4(float a, float b, float c, float d) {
    __hip_bfloat162 lo = __float22bfloat162_rn(float2{a, b});
    __hip_bfloat162 hi = __float22bfloat162_rn(float2{c, d});
    union { __hip_bfloat162 h2[2]; s16x4 v; } u;
    u.h2[0] = lo; u.h2[1] = hi;
    return u.v;
}

static __device__ __forceinline__ f32x4 unpack_bf16x4(s16x4 p) {
    union { s16x4 v; unsigned u[2]; } u; u.v = p;
    f32x4 r;
    r[0] = __uint_as_float(u.u[0] << 16);
    r[1] = __uint_as_float(u.u[0] & 0xffff0000u);
    r[2] = __uint_as_float(u.u[1] << 16);
    r[3] = __uint_as_float(u.u[1] & 0xffff0000u);
    return r;
}

// ---------------------------------------------------------------------------
// K_pre: pe[g][t][q*64 + s*4 + r] = bf16(exp(h[g*16+s][t][4q+r])).
// Transposed so the fwd wave's per-step B-fragment load is ONE contiguous
// 512B wave access (lane(q,s) -> offset q*128B + s*8B). 2048 waves.
// ---------------------------------------------------------------------------
__global__ __launch_bounds__(256) void crf_pre_kernel(
    const float* __restrict__ h, short* __restrict__ pe)
{
    int wid  = (blockIdx.x * blockDim.x + threadIdx.x) >> 6;  // 0..2047
    int lane = threadIdx.x & 63;
    int s = lane & 15, q = lane >> 4;
    int g = wid >> 5, tb = (wid & 31) * 16;
    const float* hp = h + ((size_t)(g * 16 + s) * Tn) * K + 4 * q;
    short* pp = pe + ((size_t)g * Tn) * 256 + q * 64 + s * 4;
#pragma unroll
    for (int it = 0; it < 16; ++it) {
        int t = tb + it;
        f32x4 hv = *(const f32x4*)(hp + (size_t)t * K);
        s16x4 pv = pack_bf16x4(__expf(hv[0]), __expf(hv[1]),
                               __expf(hv[2]), __expf(hv[3]));
        *(s16x4*)(pp + (size_t)t * 256) = pv;
    }
}

// ---------------------------------------------------------------------------
// K_len: one wave per sequence; mask is a contiguous prefix.
// ---------------------------------------------------------------------------
__global__ __launch_bounds__(256) void crf_len_kernel(
    const float* __restrict__ mask, int* __restrict__ len)
{
    int wid  = (blockIdx.x * blockDim.x + threadIdx.x) >> 6;
    int lane = threadIdx.x & 63;
    const float* m = mask + (size_t)wid * Tn;
    float s = 0.f;
#pragma unroll
    for (int k = 0; k < 8; ++k) s += m[lane + 64 * k];
#pragma unroll
    for (int off = 32; off; off >>= 1) s += __shfl_xor(s, off, 64);
    if (lane == 0) len[wid] = (int)(s + 0.5f);
}

// ---------------------------------------------------------------------------
// K_fwd: 16 seqs/wave, 64 waves. Per-step chain is ONLY
//   mfma(E, alpha) -> 4 mul (by prefetched pe) -> 2 cvt_pk -> mfma.
// All exp/transpose work moved to K_pre; pe loads prefetched 24 steps deep.
// Per-column power-of-2 rescale every 8 steps (computed at r==5, applied
// exactly via 2^-pend folded into pe32[0] of the next sub-block); freeze is
// an off-chain cndmask snapshot (Cfin/esumfin). Same verified logic as R2.
// ---------------------------------------------------------------------------
__global__ __launch_bounds__(64) void crf_fwd_kernel(
    const short* __restrict__ pe, const float* __restrict__ trans,
    const int* __restrict__ len, float* __restrict__ fpart)
{
    int lane = threadIdx.x;
    int s = lane & 15, q = lane >> 4;
    int g = blockIdx.x;

    // A-fragment: E[m=lane&15][k=4q+r]; exp(-10000) -> 0 exactly
    s16x4 afrag = pack_bf16x4(__expf(trans[s * K + 4 * q + 0]),
                              __expf(trans[s * K + 4 * q + 1]),
                              __expf(trans[s * K + 4 * q + 2]),
                              __expf(trans[s * K + 4 * q + 3]));
    float Estop[4];
#pragma unroll
    for (int r = 0; r < 4; ++r)
        Estop[r] = __expf(trans[STOP_ID * K + 4 * q + r]);

    int lenm1 = len[g * 16 + s] - 1;          // len >= 1 guaranteed
    int mx = lenm1;
#pragma unroll
    for (int off = 1; off < 16; off <<= 1) mx = max(mx, __shfl_xor(mx, off, 16));
    int Tmax = mx + 1;

    s16x4 bfrag;                              // alpha0 = e_START
#pragma unroll
    for (int r = 0; r < 4; ++r)
        ((short*)&bfrag)[r] = (4 * q + r == START_ID) ? (short)0x3F80 : (short)0;

    f32x4 Cfin = {0.f, 0.f, 0.f, 0.f};
    int esum = 0, esumfin = 0, pend = 0;

    const short* pp = pe + ((size_t)g * Tn) * 256 + q * 64 + s * 4;

    s16x4 nbA[8], nbB[8], nbC[8];
#pragma unroll
    for (int r = 0; r < 8; ++r) {
        nbA[r] = *(const s16x4*)(pp + (size_t)(r)      * 256);
        nbB[r] = *(const s16x4*)(pp + (size_t)(8 + r)  * 256);
        nbC[r] = *(const s16x4*)(pp + (size_t)(16 + r) * 256);
    }

    auto subblock = [&](s16x4 (&nb)[8], int tb) {
        esum += pend;
        float sc2 = __uint_as_float((unsigned)(127 - pend) << 23);  // exact 2^-pend
        f32x4 pe32[8];
#pragma unroll
        for (int r = 0; r < 8; ++r) pe32[r] = unpack_bf16x4(nb[r]);
#pragma unroll
        for (int c2 = 0; c2 < 4; ++c2) pe32[0][c2] *= sc2;
        // prefetch 3 sub-blocks (24 steps) ahead; clamp keeps loads in-buffer
#pragma unroll
        for (int r = 0; r < 8; ++r) {
            int tt = tb + 24 + r; tt = tt > Tn - 1 ? Tn - 1 : tt;
            nb[r] = *(const s16x4*)(pp + (size_t)tt * 256);
        }
#pragma unroll
        for (int r = 0; r < 8; ++r) {
            f32x4 C = __builtin_amdgcn_mfma_f32_16x16x16bf16_1k(
                afrag, bfrag, (f32x4){0.f, 0.f, 0.f, 0.f}, 0, 0, 0);
#pragma unroll
            for (int c2 = 0; c2 < 4; ++c2) C[c2] *= pe32[r][c2];
            bool fz = (tb + r == lenm1);       // off-chain freeze snapshot
#pragma unroll
            for (int c2 = 0; c2 < 4; ++c2) Cfin[c2] = fz ? C[c2] : Cfin[c2];
            esumfin = fz ? esum : esumfin;
            if (r == 5) {                      // per-column max -> pending 2^e
                float m4 = fmaxf(fmaxf(C[0], C[1]), fmaxf(C[2], C[3]));
                m4 = fmaxf(m4, __shfl_xor(m4, 16, 64));
                m4 = fmaxf(m4, __shfl_xor(m4, 32, 64));
                int e = (int)(__float_as_uint(m4) >> 23) - 127;
                pend = e < -126 ? -126 : (e > 126 ? 126 : e);
            }
            bfrag = pack_bf16x4(C[0], C[1], C[2], C[3]);
        }
    };

    for (int t0 = 0; t0 < Tmax; t0 += 24) {
        subblock(nbA, t0);
        subblock(nbB, t0 + 8);
        subblock(nbC, t0 + 16);
    }

    float part = Cfin[0] * Estop[0] + Cfin[1] * Estop[1]
               + Cfin[2] * Estop[2] + Cfin[3] * Estop[3];
    part += __shfl_xor(part, 16, 64);
    part += __shfl_xor(part, 32, 64);
    float fwd = (float)esumfin * LN2 + __logf(part);
    float v = (q == 0) ? fwd : 0.f;
#pragma unroll
    for (int off = 32; off; off >>= 1) v += __shfl_xor(v, off, 64);
    if (lane == 0) fpart[g] = v;
}

// ---------------------------------------------------------------------------
// K_gold: 512 blocks x 256 threads, 4 elements/thread; block partial ->
// gpart[block]. NO same-address atomics (that was 59us of serialization).
// ---------------------------------------------------------------------------
__global__ __launch_bounds__(256) void crf_gold_kernel(
    const float* __restrict__ h, const int* __restrict__ y,
    const float* __restrict__ mask, const float* __restrict__ trans,
    float* __restrict__ gpart)
{
    int tid = blockIdx.x * 256 + threadIdx.x;
    float gsum = 0.f;
#pragma unroll
    for (int it = 0; it < 4; ++it) {
        int idx = tid + it * (Bn * Tn / 4);
        int t = idx & (Tn - 1);
        if (mask[idx] > 0.5f) {
            int yt = y[idx];
            int yp = (t == 0) ? START_ID : y[idx - 1];
            float v = h[(size_t)idx * K + yt] + trans[yt * K + yp];
            bool last = (t == Tn - 1) || (mask[idx + 1] <= 0.5f);
            if (last) v += trans[STOP_ID * K + yt];
            gsum += v;
        }
    }
#pragma unroll
    for (int off = 32; off; off >>= 1) gsum += __shfl_xor(gsum, off, 64);
    __shared__ float red[4];
    if ((threadIdx.x & 63) == 0) red[threadIdx.x >> 6] = gsum;
    __syncthreads();
    if (threadIdx.x == 0)
        gpart[blockIdx.x] = red[0] + red[1] + red[2] + red[3];
}

// ---------------------------------------------------------------------------
// K_final: one block reduces 512 gold partials + 64 fwd partials, publishes.
// ---------------------------------------------------------------------------
__global__ __launch_bounds__(256) void crf_final_kernel(
    const float* __restrict__ fpart, const float* __restrict__ gpart,
    float* __restrict__ out)
{
    int t = threadIdx.x;
    float v = -(gpart[t] + gpart[t + 256]);
    if (t < NG) v += fpart[t];
#pragma unroll
    for (int off = 32; off; off >>= 1) v += __shfl_xor(v, off, 64);
    __shared__ float red[4];
    if ((t & 63) == 0) red[t >> 6] = v;
    __syncthreads();
    if (t == 0) out[0] = (red[0] + red[1] + red[2] + red[3]) * (1.0f / Bn);
}

extern "C" void kernel_launch(void* const* d_in, const int* in_sizes, int n_in,
                              void* d_out, int out_size, void* d_ws, size_t ws_size,
                              hipStream_t stream)
{
    const float* h     = (const float*)d_in[0];
    const int*   y     = (const int*)d_in[1];
    const float* mask  = (const float*)d_in[2];
    const float* trans = (const float*)d_in[3];
    float* out = (float*)d_out;

    // ws layout: len[1024] (int) | fpart[64] | gpart[512] | pad | pe (16 MB bf16)
    int*   len   = (int*)d_ws;
    float* fpart = (float*)d_ws + 1024;
    float* gpart = (float*)d_ws + 1088;
    short* pe    = (short*)((float*)d_ws + 4096);

    crf_pre_kernel<<<512, 256, 0, stream>>>(h, pe);
    crf_len_kernel<<<Bn / 4, 256, 0, stream>>>(mask, len);
    crf_gold_kernel<<<512, 256, 0, stream>>>(h, y, mask, trans, gpart);
    crf_fwd_kernel<<<NG, 64, 0, stream>>>(pe, trans, len, fpart);
    crf_final_kernel<<<1, 256, 0, stream>>>(fpart, gpart, out);
}

// Round 4
// 111.633 us; speedup vs baseline: 1.6507x; 1.2401x over previous
//
#include <hip/hip_runtime.h>
#include <hip/hip_bf16.h>

#define K 16
#define Bn 1024
#define Tn 512
#define START_ID 14
#define STOP_ID 15
#define LN2 0.69314718055994530942f
#define NCH 8          // chunks per sequence
#define CL 64          // chunk length

typedef float f32x4 __attribute__((ext_vector_type(4)));
typedef short s16x4 __attribute__((ext_vector_type(4)));

static __device__ __forceinline__ s16x4 pack_bf16x4(float a, float b, float c, float d) {
    __hip_bfloat162 lo = __float22bfloat162_rn(float2{a, b});
    __hip_bfloat162 hi = __float22bfloat162_rn(float2{c, d});
    union { __hip_bfloat162 h2[2]; s16x4 v; } u;
    u.h2[0] = lo; u.h2[1] = hi;
    return u.v;
}

static __device__ __forceinline__ f32x4 unpack_bf16x4(s16x4 p) {
    union { s16x4 v; unsigned u[2]; } u; u.v = p;
    f32x4 r;
    r[0] = __uint_as_float(u.u[0] << 16);
    r[1] = __uint_as_float(u.u[0] & 0xffff0000u);
    r[2] = __uint_as_float(u.u[1] << 16);
    r[3] = __uint_as_float(u.u[1] & 0xffff0000u);
    return r;
}

// ---------------------------------------------------------------------------
// K1 (fused): one thread per (b,t). Reads h[b][t][:] once (64B/thread,
// coalesced), writes pe[idx][j] = bf16(exp(h)) (32B/thread), and computes the
// gold-score contribution -> per-block partial (no same-address atomics).
// ---------------------------------------------------------------------------
__global__ __launch_bounds__(256) void crf_pre_gold(
    const float* __restrict__ h, const int* __restrict__ y,
    const float* __restrict__ mask, const float* __restrict__ trans,
    short* __restrict__ pe, float* __restrict__ gpart)
{
    int idx = blockIdx.x * 256 + threadIdx.x;      // 0 .. B*T-1
    const float* hp = h + (size_t)idx * K;
    f32x4 h0 = *(const f32x4*)(hp);
    f32x4 h1 = *(const f32x4*)(hp + 4);
    f32x4 h2 = *(const f32x4*)(hp + 8);
    f32x4 h3 = *(const f32x4*)(hp + 12);
    s16x4* pp = (s16x4*)(pe + (size_t)idx * K);
    pp[0] = pack_bf16x4(__expf(h0[0]), __expf(h0[1]), __expf(h0[2]), __expf(h0[3]));
    pp[1] = pack_bf16x4(__expf(h1[0]), __expf(h1[1]), __expf(h1[2]), __expf(h1[3]));
    pp[2] = pack_bf16x4(__expf(h2[0]), __expf(h2[1]), __expf(h2[2]), __expf(h2[3]));
    pp[3] = pack_bf16x4(__expf(h3[0]), __expf(h3[1]), __expf(h3[2]), __expf(h3[3]));

    int t = idx & (Tn - 1);
    float g = 0.f;
    if (mask[idx] > 0.5f) {
        int yt = y[idx];
        int yp = (t == 0) ? START_ID : y[idx - 1];
        g = hp[yt] + trans[yt * K + yp];
        bool last = (t == Tn - 1) || (mask[idx + 1] <= 0.5f);
        if (last) g += trans[STOP_ID * K + yt];
    }
#pragma unroll
    for (int off = 32; off; off >>= 1) g += __shfl_xor(g, off, 64);
    __shared__ float red[4];
    if ((threadIdx.x & 63) == 0) red[threadIdx.x >> 6] = g;
    __syncthreads();
    if (threadIdx.x == 0)
        gpart[blockIdx.x] = red[0] + red[1] + red[2] + red[3];
}

// ---------------------------------------------------------------------------
// K2: one wave per (b, chunk c). Evolves the 16x16 linear-space transfer
// matrix P <- (D_t E) P over the chunk's nv valid steps (nv is wave-uniform).
// One mfma/step; C/D feeds back as B with 2 cvt_pk. Per-COLUMN power-of-2
// rescale every 8 steps (computed off-chain at r==5, applied exactly at the
// next sub-block start); per-column exponent sums -> Eout. 8192 waves.
// ---------------------------------------------------------------------------
__global__ __launch_bounds__(256) void crf_chunkA(
    const short* __restrict__ pe, const float* __restrict__ mask,
    const float* __restrict__ trans, float* __restrict__ Pout,
    float* __restrict__ Eout)
{
    int lane = threadIdx.x & 63;
    int wid  = (blockIdx.x * 256 + threadIdx.x) >> 6;   // 0..8191
    int b = wid >> 3, c = wid & 7;
    int s = lane & 15, q = lane >> 4;                   // s: col(B/C-D) & row(A)

    // valid steps in this chunk (mask is a contiguous prefix over t)
    float mv = mask[(size_t)b * Tn + c * CL + lane];
    unsigned long long bal = __ballot(mv > 0.5f);
    int nv = __popcll(bal);

    // A-fragment: E[m=lane&15][k=4q+r]; exp(-10000) -> 0 exactly
    s16x4 afrag = pack_bf16x4(__expf(trans[s * K + 4 * q + 0]),
                              __expf(trans[s * K + 4 * q + 1]),
                              __expf(trans[s * K + 4 * q + 2]),
                              __expf(trans[s * K + 4 * q + 3]));

    // P = I; B-fragment = I (bf16 1.0 = 0x3F80)
    f32x4 P;
    s16x4 bfrag;
#pragma unroll
    for (int r = 0; r < 4; ++r) {
        P[r] = (4 * q + r == s) ? 1.0f : 0.0f;
        ((short*)&bfrag)[r] = (4 * q + r == s) ? (short)0x3F80 : (short)0;
    }

    int esum = 0, pend = 0;
    const short* pb = pe + ((size_t)(b * Tn + c * CL)) * K + 4 * q;

    s16x4 cur[8], nxt[8];
#pragma unroll
    for (int r = 0; r < 8; ++r)
        cur[r] = *(const s16x4*)(pb + (size_t)r * K);

    for (int sb = 0; sb < 8; ++sb) {
        int base = sb * 8;
        if (base >= nv) break;                 // wave-uniform
        int n = nv - base; if (n > 8) n = 8;

        esum += pend;
        float sc = __uint_as_float((unsigned)(127 - pend) << 23); // exact 2^-pend
        pend = 0;
        f32x4 pef[8];
#pragma unroll
        for (int r = 0; r < 8; ++r) pef[r] = unpack_bf16x4(cur[r]);
#pragma unroll
        for (int c2 = 0; c2 < 4; ++c2) pef[0][c2] *= sc;
        // prefetch next sub-block (clamped to chunk end; pe always in-bounds)
#pragma unroll
        for (int r = 0; r < 8; ++r) {
            int tt = base + 8 + r; tt = tt > CL - 1 ? CL - 1 : tt;
            nxt[r] = *(const s16x4*)(pb + (size_t)tt * K);
        }
#pragma unroll
        for (int r = 0; r < 8; ++r) {
            if (r >= n) break;                 // wave-uniform
            f32x4 C = __builtin_amdgcn_mfma_f32_16x16x16bf16_1k(
                afrag, bfrag, (f32x4){0.f, 0.f, 0.f, 0.f}, 0, 0, 0);
#pragma unroll
            for (int c2 = 0; c2 < 4; ++c2) C[c2] *= pef[r][c2];
            if (r == 5) {                      // per-column max -> pending 2^e
                float m4 = fmaxf(fmaxf(C[0], C[1]), fmaxf(C[2], C[3]));
                m4 = fmaxf(m4, __shfl_xor(m4, 16, 64));
                m4 = fmaxf(m4, __shfl_xor(m4, 32, 64));
                int e = (int)(__float_as_uint(m4) >> 23) - 127;
                pend = e < -126 ? -126 : (e > 126 ? 126 : e);
            }
            bfrag = pack_bf16x4(C[0], C[1], C[2], C[3]);
            P = C;
        }
#pragma unroll
        for (int r = 0; r < 8; ++r) cur[r] = nxt[r];
    }

    // store P~ (row-major [row][col]) and per-column exponent
    float* Pp = Pout + (size_t)wid * 256;
#pragma unroll
    for (int r = 0; r < 4; ++r)
        Pp[(4 * q + r) * K + s] = P[r];
    if (q == 0) Eout[wid * K + s] = (float)esum;
}

// ---------------------------------------------------------------------------
// K3: one wave per sequence. alpha = e_START; for each chunk:
//   alpha' = P~ * (ldexp(alpha_i, e_i - max_e))  [f32 matvec, shuffle-reduce]
// with running log (ls). Then fwd = ls + log(sum alpha_j * exp(trans[STOP,j])).
// ---------------------------------------------------------------------------
__global__ __launch_bounds__(256) void crf_combine(
    const float* __restrict__ Pin, const float* __restrict__ Ein,
    const float* __restrict__ trans, float* __restrict__ fpart)
{
    int lane = threadIdx.x & 63;
    int b = blockIdx.x * 4 + (threadIdx.x >> 6);
    int j = lane & 15, q = lane >> 4;

    f32x4 Prow[NCH], Er[NCH];
#pragma unroll
    for (int c = 0; c < NCH; ++c) {
        Prow[c] = *(const f32x4*)(Pin + (size_t)(b * NCH + c) * 256 + j * K + 4 * q);
        Er[c]   = *(const f32x4*)(Ein + (size_t)(b * NCH + c) * K + 4 * q);
    }
    float Estop[4];
#pragma unroll
    for (int r = 0; r < 4; ++r)
        Estop[r] = __expf(trans[STOP_ID * K + 4 * q + r]);

    float ap[4];
#pragma unroll
    for (int r = 0; r < 4; ++r) ap[r] = (4 * q + r == START_ID) ? 1.0f : 0.0f;
    float ls = 0.f;

#pragma unroll
    for (int c = 0; c < NCH; ++c) {
        float me = fmaxf(fmaxf(Er[c][0], Er[c][1]), fmaxf(Er[c][2], Er[c][3]));
        me = fmaxf(me, __shfl_xor(me, 16, 64));
        me = fmaxf(me, __shfl_xor(me, 32, 64));
        float w0 = ldexpf(ap[0], (int)(Er[c][0] - me));
        float w1 = ldexpf(ap[1], (int)(Er[c][1] - me));
        float w2 = ldexpf(ap[2], (int)(Er[c][2] - me));
        float w3 = ldexpf(ap[3], (int)(Er[c][3] - me));
        float acc = Prow[c][0]*w0 + Prow[c][1]*w1 + Prow[c][2]*w2 + Prow[c][3]*w3;
        acc += __shfl_xor(acc, 16, 64);
        acc += __shfl_xor(acc, 32, 64);        // alpha'[j] at every lane
        float mj = acc;
#pragma unroll
        for (int off = 1; off < 16; off <<= 1)
            mj = fmaxf(mj, __shfl_xor(mj, off, 64));
        ls += me * LN2 + __logf(mj);
        float an = acc * (1.0f / mj);
#pragma unroll
        for (int r = 0; r < 4; ++r)
            ap[r] = __shfl(an, q * 4 + r, 16);
    }

    float part = ap[0]*Estop[0] + ap[1]*Estop[1] + ap[2]*Estop[2] + ap[3]*Estop[3];
    part += __shfl_xor(part, 16, 64);
    part += __shfl_xor(part, 32, 64);
    float fwd = ls + __logf(part);
    if (lane == 0) fpart[b] = fwd;
}

// ---------------------------------------------------------------------------
// K4: one block reduces 1024 fwd partials - 2048 gold partials, publishes.
// ---------------------------------------------------------------------------
__global__ __launch_bounds__(256) void crf_final(
    const float* __restrict__ fpart, const float* __restrict__ gpart,
    float* __restrict__ out)
{
    int t = threadIdx.x;
    float v = 0.f;
#pragma unroll
    for (int k2 = 0; k2 < 4; ++k2) v += fpart[t + 256 * k2];
#pragma unroll
    for (int k2 = 0; k2 < 8; ++k2) v -= gpart[t + 256 * k2];
#pragma unroll
    for (int off = 32; off; off >>= 1) v += __shfl_xor(v, off, 64);
    __shared__ float red[4];
    if ((t & 63) == 0) red[t >> 6] = v;
    __syncthreads();
    if (t == 0) out[0] = (red[0] + red[1] + red[2] + red[3]) * (1.0f / Bn);
}

extern "C" void kernel_launch(void* const* d_in, const int* in_sizes, int n_in,
                              void* d_out, int out_size, void* d_ws, size_t ws_size,
                              hipStream_t stream)
{
    const float* h     = (const float*)d_in[0];
    const int*   y     = (const int*)d_in[1];
    const float* mask  = (const float*)d_in[2];
    const float* trans = (const float*)d_in[3];
    float* out = (float*)d_out;

    // ws layout: pe 16MB | Pout 8MB | Eout 0.5MB | gpart 8KB | fpart 4KB
    short* pe    = (short*)d_ws;                                  // B*T*16 bf16
    float* Pout  = (float*)((char*)d_ws + (size_t)Bn * Tn * K * 2);
    float* Eout  = Pout + (size_t)Bn * NCH * 256;
    float* gpart = Eout + (size_t)Bn * NCH * K;
    float* fpart = gpart + 2048;

    crf_pre_gold<<<(Bn * Tn) / 256, 256, 0, stream>>>(h, y, mask, trans, pe, gpart);
    crf_chunkA<<<(Bn * NCH) / 4, 256, 0, stream>>>(pe, mask, trans, Pout, Eout);
    crf_combine<<<Bn / 4, 256, 0, stream>>>(Pout, Eout, trans, fpart);
    crf_final<<<1, 256, 0, stream>>>(fpart, gpart, out);
}

// Round 5
// 107.775 us; speedup vs baseline: 1.7098x; 1.0358x over previous
//
#include <hip/hip_runtime.h>
#include <hip/hip_bf16.h>

#define K 16
#define Bn 1024
#define Tn 512
#define START_ID 14
#define STOP_ID 15
#define LN2 0.69314718055994530942f
#define NCH 4          // chunks per sequence (one block = one sequence)
#define CL 128         // chunk length

typedef float f32x4 __attribute__((ext_vector_type(4)));
typedef short s16x4 __attribute__((ext_vector_type(4)));

static __device__ __forceinline__ s16x4 pack_bf16x4(float a, float b, float c, float d) {
    __hip_bfloat162 lo = __float22bfloat162_rn(float2{a, b});
    __hip_bfloat162 hi = __float22bfloat162_rn(float2{c, d});
    union { __hip_bfloat162 h2[2]; s16x4 v; } u;
    u.h2[0] = lo; u.h2[1] = hi;
    return u.v;
}

static __device__ __forceinline__ f32x4 unpack_bf16x4(s16x4 p) {
    union { s16x4 v; unsigned u[2]; } u; u.v = p;
    f32x4 r;
    r[0] = __uint_as_float(u.u[0] << 16);
    r[1] = __uint_as_float(u.u[0] & 0xffff0000u);
    r[2] = __uint_as_float(u.u[1] << 16);
    r[3] = __uint_as_float(u.u[1] & 0xffff0000u);
    return r;
}

// ---------------------------------------------------------------------------
// K1: one thread per (b,t). Reads h once (64B/thread, coalesced), writes
// pe = bf16(exp(h)) (32B/thread), computes gold contribution -> block partial.
// Validity from y != PAD (exact: y==0 <=> mask==0) -- no mask reads at all.
// ---------------------------------------------------------------------------
__global__ __launch_bounds__(256) void crf_pre_gold(
    const float* __restrict__ h, const int* __restrict__ y,
    const float* __restrict__ trans,
    short* __restrict__ pe, float* __restrict__ gpart)
{
    int idx = blockIdx.x * 256 + threadIdx.x;      // 0 .. B*T-1
    const float* hp = h + (size_t)idx * K;
    f32x4 h0 = *(const f32x4*)(hp);
    f32x4 h1 = *(const f32x4*)(hp + 4);
    f32x4 h2 = *(const f32x4*)(hp + 8);
    f32x4 h3 = *(const f32x4*)(hp + 12);
    s16x4* pp = (s16x4*)(pe + (size_t)idx * K);
    pp[0] = pack_bf16x4(__expf(h0[0]), __expf(h0[1]), __expf(h0[2]), __expf(h0[3]));
    pp[1] = pack_bf16x4(__expf(h1[0]), __expf(h1[1]), __expf(h1[2]), __expf(h1[3]));
    pp[2] = pack_bf16x4(__expf(h2[0]), __expf(h2[1]), __expf(h2[2]), __expf(h2[3]));
    pp[3] = pack_bf16x4(__expf(h3[0]), __expf(h3[1]), __expf(h3[2]), __expf(h3[3]));

    int t = idx & (Tn - 1);
    int yt = y[idx];
    float g = 0.f;
    if (yt != 0) {
        int yp = (t == 0) ? START_ID : y[idx - 1];
        g = hp[yt] + trans[yt * K + yp];
        bool last = (t == Tn - 1) || (y[idx + 1] == 0);
        if (last) g += trans[STOP_ID * K + yt];
    }
#pragma unroll
    for (int off = 32; off; off >>= 1) g += __shfl_xor(g, off, 64);
    __shared__ float red[4];
    if ((threadIdx.x & 63) == 0) red[threadIdx.x >> 6] = g;
    __syncthreads();
    if (threadIdx.x == 0)
        gpart[blockIdx.x] = red[0] + red[1] + red[2] + red[3];
}

// ---------------------------------------------------------------------------
// K2: one BLOCK per sequence; wave c (0..3) evolves the 16x16 linear-space
// transfer matrix of chunk c (128 steps): P <- (D_t E) P, one mfma/step,
// C/D feedback as B via 2 cvt_pk. Per-COLUMN power-of-2 rescale every 8
// steps (computed off-chain at r==5, applied exactly next sub-block).
// P/esum -> LDS -> wave 0 runs the combine (R4-verified math, NCH=4) and
// writes fpart[b]. No global P/E traffic, no separate combine kernel.
// ---------------------------------------------------------------------------
__global__ __launch_bounds__(256) void crf_chunk_combine(
    const short* __restrict__ pe, const int* __restrict__ y,
    const float* __restrict__ trans, float* __restrict__ fpart)
{
    __shared__ float Pl[NCH][16][17];   // [chunk][row][col], +1 pad
    __shared__ float El[NCH][16];       // per-column exponent sums

    int lane = threadIdx.x & 63;
    int c = threadIdx.x >> 6;           // wave id == chunk id
    int b = blockIdx.x;
    int s = lane & 15, q = lane >> 4;

    // valid steps in this chunk (y!=0 is a contiguous prefix over t)
    const int* yb = y + (size_t)b * Tn + c * CL;
    unsigned long long bal0 = __ballot(yb[lane] != 0);
    unsigned long long bal1 = __ballot(yb[64 + lane] != 0);
    int nv = __popcll(bal0) + __popcll(bal1);

    // A-fragment: E[m=lane&15][k=4q+r]; exp(-10000) -> 0 exactly
    s16x4 afrag = pack_bf16x4(__expf(trans[s * K + 4 * q + 0]),
                              __expf(trans[s * K + 4 * q + 1]),
                              __expf(trans[s * K + 4 * q + 2]),
                              __expf(trans[s * K + 4 * q + 3]));

    // P = I; B-fragment = I (bf16 1.0 = 0x3F80)
    f32x4 P;
    s16x4 bfrag;
#pragma unroll
    for (int r = 0; r < 4; ++r) {
        P[r] = (4 * q + r == s) ? 1.0f : 0.0f;
        ((short*)&bfrag)[r] = (4 * q + r == s) ? (short)0x3F80 : (short)0;
    }

    int esum = 0, pend = 0;
    const short* pb = pe + ((size_t)(b * Tn + c * CL)) * K + 4 * q;

    s16x4 cur[8], nxt[8];
#pragma unroll
    for (int r = 0; r < 8; ++r)
        cur[r] = *(const s16x4*)(pb + (size_t)r * K);

    for (int sb = 0; sb < CL / 8; ++sb) {
        int base = sb * 8;
        if (base >= nv) break;                 // wave-uniform
        int n = nv - base; if (n > 8) n = 8;

        esum += pend;
        float sc = __uint_as_float((unsigned)(127 - pend) << 23); // exact 2^-pend
        pend = 0;
        f32x4 pef[8];
#pragma unroll
        for (int r = 0; r < 8; ++r) pef[r] = unpack_bf16x4(cur[r]);
#pragma unroll
        for (int c2 = 0; c2 < 4; ++c2) pef[0][c2] *= sc;
        // prefetch next sub-block (clamped inside the chunk; always in-bounds)
#pragma unroll
        for (int r = 0; r < 8; ++r) {
            int tt = base + 8 + r; tt = tt > CL - 1 ? CL - 1 : tt;
            nxt[r] = *(const s16x4*)(pb + (size_t)tt * K);
        }
#pragma unroll
        for (int r = 0; r < 8; ++r) {
            if (r >= n) break;                 // wave-uniform
            f32x4 C = __builtin_amdgcn_mfma_f32_16x16x16bf16_1k(
                afrag, bfrag, (f32x4){0.f, 0.f, 0.f, 0.f}, 0, 0, 0);
#pragma unroll
            for (int c2 = 0; c2 < 4; ++c2) C[c2] *= pef[r][c2];
            if (r == 5) {                      // per-column max -> pending 2^e
                float m4 = fmaxf(fmaxf(C[0], C[1]), fmaxf(C[2], C[3]));
                m4 = fmaxf(m4, __shfl_xor(m4, 16, 64));
                m4 = fmaxf(m4, __shfl_xor(m4, 32, 64));
                int e = (int)(__float_as_uint(m4) >> 23) - 127;
                pend = e < -126 ? -126 : (e > 126 ? 126 : e);
            }
            bfrag = pack_bf16x4(C[0], C[1], C[2], C[3]);
            P = C;
        }
#pragma unroll
        for (int r = 0; r < 8; ++r) cur[r] = nxt[r];
    }

    // publish chunk result to LDS
#pragma unroll
    for (int r = 0; r < 4; ++r)
        Pl[c][4 * q + r][s] = P[r];
    if (q == 0) El[c][s] = (float)esum;
    __syncthreads();

    // ---- combine (wave 0 only): alpha = e_START; alpha' = P~ * ldexp(w) ----
    if (c == 0) {
        int j = s;                              // row index for this lane
        f32x4 Prow[NCH], Er[NCH];
#pragma unroll
        for (int cc = 0; cc < NCH; ++cc) {
#pragma unroll
            for (int r = 0; r < 4; ++r) {
                Prow[cc][r] = Pl[cc][j][4 * q + r];
                Er[cc][r]   = El[cc][4 * q + r];
            }
        }
        float Estop[4];
#pragma unroll
        for (int r = 0; r < 4; ++r)
            Estop[r] = __expf(trans[STOP_ID * K + 4 * q + r]);

        float ap[4];
#pragma unroll
        for (int r = 0; r < 4; ++r) ap[r] = (4 * q + r == START_ID) ? 1.0f : 0.0f;
        float ls = 0.f;

#pragma unroll
        for (int cc = 0; cc < NCH; ++cc) {
            float me = fmaxf(fmaxf(Er[cc][0], Er[cc][1]), fmaxf(Er[cc][2], Er[cc][3]));
            me = fmaxf(me, __shfl_xor(me, 16, 64));
            me = fmaxf(me, __shfl_xor(me, 32, 64));
            float w0 = ldexpf(ap[0], (int)(Er[cc][0] - me));
            float w1 = ldexpf(ap[1], (int)(Er[cc][1] - me));
            float w2 = ldexpf(ap[2], (int)(Er[cc][2] - me));
            float w3 = ldexpf(ap[3], (int)(Er[cc][3] - me));
            float acc = Prow[cc][0]*w0 + Prow[cc][1]*w1
                      + Prow[cc][2]*w2 + Prow[cc][3]*w3;
            acc += __shfl_xor(acc, 16, 64);
            acc += __shfl_xor(acc, 32, 64);    // alpha'[j] at every lane
            float mj = acc;
#pragma unroll
            for (int off = 1; off < 16; off <<= 1)
                mj = fmaxf(mj, __shfl_xor(mj, off, 64));
            ls += me * LN2 + __logf(mj);
            float an = acc * (1.0f / mj);
#pragma unroll
            for (int r = 0; r < 4; ++r)
                ap[r] = __shfl(an, q * 4 + r, 16);
        }

        float part = ap[0]*Estop[0] + ap[1]*Estop[1]
                   + ap[2]*Estop[2] + ap[3]*Estop[3];
        part += __shfl_xor(part, 16, 64);
        part += __shfl_xor(part, 32, 64);
        if (lane == 0) fpart[b] = ls + __logf(part);
    }
}

// ---------------------------------------------------------------------------
// K3: one block reduces 1024 fwd partials - 2048 gold partials, publishes.
// ---------------------------------------------------------------------------
__global__ __launch_bounds__(256) void crf_final(
    const float* __restrict__ fpart, const float* __restrict__ gpart,
    float* __restrict__ out)
{
    int t = threadIdx.x;
    float v = 0.f;
#pragma unroll
    for (int k2 = 0; k2 < 4; ++k2) v += fpart[t + 256 * k2];
#pragma unroll
    for (int k2 = 0; k2 < 8; ++k2) v -= gpart[t + 256 * k2];
#pragma unroll
    for (int off = 32; off; off >>= 1) v += __shfl_xor(v, off, 64);
    __shared__ float red[4];
    if ((t & 63) == 0) red[t >> 6] = v;
    __syncthreads();
    if (t == 0) out[0] = (red[0] + red[1] + red[2] + red[3]) * (1.0f / Bn);
}

extern "C" void kernel_launch(void* const* d_in, const int* in_sizes, int n_in,
                              void* d_out, int out_size, void* d_ws, size_t ws_size,
                              hipStream_t stream)
{
    const float* h     = (const float*)d_in[0];
    const int*   y     = (const int*)d_in[1];
    const float* trans = (const float*)d_in[3];
    float* out = (float*)d_out;

    // ws layout: gpart[2048] | fpart[1024] | pad->4096 | pe (16 MB bf16)
    float* gpart = (float*)d_ws;
    float* fpart = gpart + 2048;
    short* pe    = (short*)((float*)d_ws + 4096);

    crf_pre_gold<<<(Bn * Tn) / 256, 256, 0, stream>>>(h, y, trans, pe, gpart);
    crf_chunk_combine<<<Bn, 256, 0, stream>>>(pe, y, trans, fpart);
    crf_final<<<1, 256, 0, stream>>>(fpart, gpart, out);
}

// Round 6
// 106.738 us; speedup vs baseline: 1.7264x; 1.0097x over previous
//
#include <hip/hip_runtime.h>
#include <hip/hip_bf16.h>

#define K 16
#define Bn 1024
#define Tn 512
#define START_ID 14
#define STOP_ID 15
#define LN2 0.69314718055994530942f
#define NCH 4          // chunks per sequence (one block = one sequence)
#define CL 128         // chunk length

typedef float f32x4 __attribute__((ext_vector_type(4)));
typedef short s16x4 __attribute__((ext_vector_type(4)));

static __device__ __forceinline__ s16x4 pack_bf16x4(float a, float b, float c, float d) {
    __hip_bfloat162 lo = __float22bfloat162_rn(float2{a, b});
    __hip_bfloat162 hi = __float22bfloat162_rn(float2{c, d});
    union { __hip_bfloat162 h2[2]; s16x4 v; } u;
    u.h2[0] = lo; u.h2[1] = hi;
    return u.v;
}

// ---------------------------------------------------------------------------
// K1: one BLOCK per sequence b; wave c (0..3) evolves chunk c's 16x16
// linear-space transfer matrix P <- (D_t E) P.  KEY CHANGE vs R5: exp(h) is
// folded into the A-operand (A[m=s][k] = exp(h[t][s]) * E[s][k]) -- the A-row
// index is the SAME lane coord as B/C's column, so only ONE exp per lane per
// step and NO pe intermediate (pre kernel deleted; h read once, broadcast).
// Per-COLUMN power-of-2 rescale every 8 steps now applied at the B-pack of
// the next sub-block (scaling B columns == scaling C columns; exact 2^-e).
// Gold score fused (runs first -> warms L2 with exactly the chain's lines).
// P/esum/gold -> LDS -> wave 0 combines (R5-verified math) and writes
// res[b] = fwd_b - gold_b.
// ---------------------------------------------------------------------------
__global__ __launch_bounds__(256) void crf_all(
    const float* __restrict__ h, const int* __restrict__ y,
    const float* __restrict__ trans, float* __restrict__ res)
{
    __shared__ float Pl[NCH][16][17];   // [chunk][row][col], +1 pad
    __shared__ float El[NCH][16];       // per-column exponent sums
    __shared__ float Gl[NCH];           // per-chunk gold partials

    int lane = threadIdx.x & 63;
    int c = threadIdx.x >> 6;           // wave id == chunk id
    int b = blockIdx.x;
    int s = lane & 15, q = lane >> 4;

    const int* yseq = y + (size_t)b * Tn;
    int y0 = yseq[c * CL + lane];
    int y1 = yseq[c * CL + 64 + lane];
    unsigned long long bal0 = __ballot(y0 != 0);
    unsigned long long bal1 = __ballot(y1 != 0);
    int nv = __popcll(bal0) + __popcll(bal1);   // valid steps (prefix)

    // ---- gold for this chunk (scattered reads; also pre-warms L2) ----
    const float* hseq = h + ((size_t)b * Tn) * K;
    float g = 0.f;
    {
        int t = c * CL + lane;
        if (y0 != 0) {
            int yp = (t == 0) ? START_ID : yseq[t - 1];
            int tn = t + 1 > Tn - 1 ? Tn - 1 : t + 1;
            float v = hseq[(size_t)t * K + y0] + trans[y0 * K + yp];
            bool last = (t == Tn - 1) || (yseq[tn] == 0);
            if (last) v += trans[STOP_ID * K + y0];
            g += v;
        }
        int t2 = c * CL + 64 + lane;
        if (y1 != 0) {
            int yp = yseq[t2 - 1];
            int tn = t2 + 1 > Tn - 1 ? Tn - 1 : t2 + 1;
            float v = hseq[(size_t)t2 * K + y1] + trans[y1 * K + yp];
            bool last = (t2 == Tn - 1) || (yseq[tn] == 0);
            if (last) v += trans[STOP_ID * K + y1];
            g += v;
        }
    }
#pragma unroll
    for (int off = 32; off; off >>= 1) g += __shfl_xor(g, off, 64);
    if (lane == 0) Gl[c] = g;

    // ---- chain: E row for this lane (f32; exp(-10000) -> 0 exactly) ----
    float E0[4];
#pragma unroll
    for (int r = 0; r < 4; ++r)
        E0[r] = __expf(trans[s * K + 4 * q + r]);

    f32x4 P;
    s16x4 bfrag;
#pragma unroll
    for (int r = 0; r < 4; ++r) {
        P[r] = (4 * q + r == s) ? 1.0f : 0.0f;
        ((short*)&bfrag)[r] = (4 * q + r == s) ? (short)0x3F80 : (short)0;
    }

    int esum = 0, pend = 0;
    const float* hcs = hseq + (size_t)c * CL * K + s;  // h[b][cCL+t][s]

    float hcur[8], hnxt[8];
#pragma unroll
    for (int r = 0; r < 8; ++r) hcur[r] = hcs[(size_t)r * K];

    for (int sb = 0; sb < CL / 8; ++sb) {
        int base = sb * 8;
        if (base >= nv) break;                 // wave-uniform
        int n = nv - base; if (n > 8) n = 8;

        esum += pend;
        float sc = __uint_as_float((unsigned)(127 - pend) << 23); // exact 2^-pend
        pend = 0;
        // apply pending per-column scale to B (cols of B == cols of C)
        P[0] *= sc; P[1] *= sc; P[2] *= sc; P[3] *= sc;
        bfrag = pack_bf16x4(P[0], P[1], P[2], P[3]);

        float es[8];
#pragma unroll
        for (int r = 0; r < 8; ++r) es[r] = __expf(hcur[r]);
        // prefetch next sub-block's h (clamped inside the chunk)
#pragma unroll
        for (int r = 0; r < 8; ++r) {
            int tt = base + 8 + r; tt = tt > CL - 1 ? CL - 1 : tt;
            hnxt[r] = hcs[(size_t)tt * K];
        }
#pragma unroll
        for (int r = 0; r < 8; ++r) {
            if (r >= n) break;                 // wave-uniform
            s16x4 afrag = pack_bf16x4(es[r] * E0[0], es[r] * E0[1],
                                      es[r] * E0[2], es[r] * E0[3]);
            f32x4 C = __builtin_amdgcn_mfma_f32_16x16x16bf16_1k(
                afrag, bfrag, (f32x4){0.f, 0.f, 0.f, 0.f}, 0, 0, 0);
            if (r == 5) {                      // per-column max -> pending 2^e
                float m4 = fmaxf(fmaxf(C[0], C[1]), fmaxf(C[2], C[3]));
                m4 = fmaxf(m4, __shfl_xor(m4, 16, 64));
                m4 = fmaxf(m4, __shfl_xor(m4, 32, 64));
                int e = (int)(__float_as_uint(m4) >> 23) - 127;
                pend = e < -126 ? -126 : (e > 126 ? 126 : e);
            }
            bfrag = pack_bf16x4(C[0], C[1], C[2], C[3]);
            P = C;
        }
#pragma unroll
        for (int r = 0; r < 8; ++r) hcur[r] = hnxt[r];
    }

    // publish chunk result to LDS
#pragma unroll
    for (int r = 0; r < 4; ++r)
        Pl[c][4 * q + r][s] = P[r];
    if (q == 0) El[c][s] = (float)esum;
    __syncthreads();

    // ---- combine (wave 0): alpha = e_START; alpha' = P~ * ldexp(w) ----
    if (c == 0) {
        int j = s;
        f32x4 Prow[NCH], Er[NCH];
#pragma unroll
        for (int cc = 0; cc < NCH; ++cc) {
#pragma unroll
            for (int r = 0; r < 4; ++r) {
                Prow[cc][r] = Pl[cc][j][4 * q + r];
                Er[cc][r]   = El[cc][4 * q + r];
            }
        }
        float Estop[4];
#pragma unroll
        for (int r = 0; r < 4; ++r)
            Estop[r] = __expf(trans[STOP_ID * K + 4 * q + r]);

        float ap[4];
#pragma unroll
        for (int r = 0; r < 4; ++r) ap[r] = (4 * q + r == START_ID) ? 1.0f : 0.0f;
        float ls = 0.f;

#pragma unroll
        for (int cc = 0; cc < NCH; ++cc) {
            float me = fmaxf(fmaxf(Er[cc][0], Er[cc][1]), fmaxf(Er[cc][2], Er[cc][3]));
            me = fmaxf(me, __shfl_xor(me, 16, 64));
            me = fmaxf(me, __shfl_xor(me, 32, 64));
            float w0 = ldexpf(ap[0], (int)(Er[cc][0] - me));
            float w1 = ldexpf(ap[1], (int)(Er[cc][1] - me));
            float w2 = ldexpf(ap[2], (int)(Er[cc][2] - me));
            float w3 = ldexpf(ap[3], (int)(Er[cc][3] - me));
            float acc = Prow[cc][0]*w0 + Prow[cc][1]*w1
                      + Prow[cc][2]*w2 + Prow[cc][3]*w3;
            acc += __shfl_xor(acc, 16, 64);
            acc += __shfl_xor(acc, 32, 64);    // alpha'[j] at every lane
            float mj = acc;
#pragma unroll
            for (int off = 1; off < 16; off <<= 1)
                mj = fmaxf(mj, __shfl_xor(mj, off, 64));
            ls += me * LN2 + __logf(mj);
            float an = acc * (1.0f / mj);
#pragma unroll
            for (int r = 0; r < 4; ++r)
                ap[r] = __shfl(an, q * 4 + r, 16);
        }

        float part = ap[0]*Estop[0] + ap[1]*Estop[1]
                   + ap[2]*Estop[2] + ap[3]*Estop[3];
        part += __shfl_xor(part, 16, 64);
        part += __shfl_xor(part, 32, 64);
        if (lane == 0)
            res[b] = ls + __logf(part) - (Gl[0] + Gl[1] + Gl[2] + Gl[3]);
    }
}

// ---------------------------------------------------------------------------
// K2: one block reduces 1024 per-sequence (fwd - gold) values, publishes mean.
// ---------------------------------------------------------------------------
__global__ __launch_bounds__(256) void crf_final(
    const float* __restrict__ res, float* __restrict__ out)
{
    int t = threadIdx.x;
    float v = 0.f;
#pragma unroll
    for (int k2 = 0; k2 < 4; ++k2) v += res[t + 256 * k2];
#pragma unroll
    for (int off = 32; off; off >>= 1) v += __shfl_xor(v, off, 64);
    __shared__ float red[4];
    if ((t & 63) == 0) red[t >> 6] = v;
    __syncthreads();
    if (t == 0) out[0] = (red[0] + red[1] + red[2] + red[3]) * (1.0f / Bn);
}

extern "C" void kernel_launch(void* const* d_in, const int* in_sizes, int n_in,
                              void* d_out, int out_size, void* d_ws, size_t ws_size,
                              hipStream_t stream)
{
    const float* h     = (const float*)d_in[0];
    const int*   y     = (const int*)d_in[1];
    const float* trans = (const float*)d_in[3];
    float* out = (float*)d_out;
    float* res = (float*)d_ws;          // 1024 floats

    crf_all<<<Bn, 256, 0, stream>>>(h, y, trans, res);
    crf_final<<<1, 256, 0, stream>>>(res, out);
}

// Round 7
// 104.803 us; speedup vs baseline: 1.7583x; 1.0185x over previous
//
#include <hip/hip_runtime.h>
#include <hip/hip_bf16.h>

#define K 16
#define Bn 1024
#define Tn 512
#define START_ID 14
#define STOP_ID 15
#define LN2 0.69314718055994530942f
#define NCH 4          // chunks per sequence (one block = one sequence)
#define CL 128         // chunk length

typedef float f32x4 __attribute__((ext_vector_type(4)));
typedef short s16x4 __attribute__((ext_vector_type(4)));

// f32x4 -> bf16x4 in 6 VALU ops (round-half-up: +0x8000 then take hi16 via
// v_perm_b32). The previous __float22bfloat162_rn lowered to ~25 VALU ops of
// RNE bit-twiddling -- run twice per chain step, it WAS the kernel (~800
// cy/step). Half-up vs RNE differs only on exact ties (bias ~2^-17 rel).
static __device__ __forceinline__ s16x4 pack_bf16x4(float a, float b, float c, float d) {
    unsigned ua = __float_as_uint(a) + 0x8000u;
    unsigned ub = __float_as_uint(b) + 0x8000u;
    unsigned uc = __float_as_uint(c) + 0x8000u;
    unsigned ud = __float_as_uint(d) + 0x8000u;
    union { unsigned u[2]; s16x4 v; } un;
    un.u[0] = __builtin_amdgcn_perm(ub, ua, 0x07060302);  // [bf16(b):bf16(a)]
    un.u[1] = __builtin_amdgcn_perm(ud, uc, 0x07060302);  // [bf16(d):bf16(c)]
    return un.v;
}

// ---------------------------------------------------------------------------
// K1: one BLOCK per sequence b; wave c (0..3) evolves chunk c's 16x16
// linear-space transfer matrix P <- (D_t E) P, exp(h) folded into the
// A-operand (A[m=s][k] = exp(h[t][s]) * E[s][k]; A-row index == B/C column
// lane coord, so ONE exp per lane per step). Per-COLUMN power-of-2 rescale
// every 8 steps (computed off-chain at r==5, applied exactly at the next
// sub-block's B-pack). Gold fused; P/esum/gold -> LDS -> wave 0 combines and
// writes res[b] = fwd_b - gold_b. h prefetched 2 sub-blocks (16 steps) deep.
// ---------------------------------------------------------------------------
__global__ __launch_bounds__(256) void crf_all(
    const float* __restrict__ h, const int* __restrict__ y,
    const float* __restrict__ trans, float* __restrict__ res)
{
    __shared__ float Pl[NCH][16][17];   // [chunk][row][col], +1 pad
    __shared__ float El[NCH][16];       // per-column exponent sums
    __shared__ float Gl[NCH];           // per-chunk gold partials

    int lane = threadIdx.x & 63;
    int c = threadIdx.x >> 6;           // wave id == chunk id
    int b = blockIdx.x;
    int s = lane & 15, q = lane >> 4;

    const int* yseq = y + (size_t)b * Tn;
    int y0 = yseq[c * CL + lane];
    int y1 = yseq[c * CL + 64 + lane];
    unsigned long long bal0 = __ballot(y0 != 0);
    unsigned long long bal1 = __ballot(y1 != 0);
    int nv = __popcll(bal0) + __popcll(bal1);   // valid steps (prefix)

    // ---- gold for this chunk (scattered reads; also pre-warms L2) ----
    const float* hseq = h + ((size_t)b * Tn) * K;
    float g = 0.f;
    {
        int t = c * CL + lane;
        if (y0 != 0) {
            int yp = (t == 0) ? START_ID : yseq[t - 1];
            int tn = t + 1 > Tn - 1 ? Tn - 1 : t + 1;
            float v = hseq[(size_t)t * K + y0] + trans[y0 * K + yp];
            bool last = (t == Tn - 1) || (yseq[tn] == 0);
            if (last) v += trans[STOP_ID * K + y0];
            g += v;
        }
        int t2 = c * CL + 64 + lane;
        if (y1 != 0) {
            int yp = yseq[t2 - 1];
            int tn = t2 + 1 > Tn - 1 ? Tn - 1 : t2 + 1;
            float v = hseq[(size_t)t2 * K + y1] + trans[y1 * K + yp];
            bool last = (t2 == Tn - 1) || (yseq[tn] == 0);
            if (last) v += trans[STOP_ID * K + y1];
            g += v;
        }
    }
#pragma unroll
    for (int off = 32; off; off >>= 1) g += __shfl_xor(g, off, 64);
    if (lane == 0) Gl[c] = g;

    // ---- chain: E row for this lane (f32; exp(-10000) -> 0 exactly) ----
    float E0[4];
#pragma unroll
    for (int r = 0; r < 4; ++r)
        E0[r] = __expf(trans[s * K + 4 * q + r]);

    f32x4 P;
    s16x4 bfrag;
#pragma unroll
    for (int r = 0; r < 4; ++r) {
        P[r] = (4 * q + r == s) ? 1.0f : 0.0f;
        ((short*)&bfrag)[r] = (4 * q + r == s) ? (short)0x3F80 : (short)0;
    }

    int esum = 0, pend = 0;
    const float* hcs = hseq + (size_t)c * CL * K + s;  // h[b][cCL+t][s]

    float hcur[8], hnx1[8], hnx2[8];
#pragma unroll
    for (int r = 0; r < 8; ++r) {
        hcur[r] = hcs[(size_t)r * K];
        hnx1[r] = hcs[(size_t)(8 + r) * K];
    }

    for (int sb = 0; sb < CL / 8; ++sb) {
        int base = sb * 8;
        if (base >= nv) break;                 // wave-uniform
        int n = nv - base; if (n > 8) n = 8;

        esum += pend;
        float sc = __uint_as_float((unsigned)(127 - pend) << 23); // exact 2^-pend
        pend = 0;
        // apply pending per-column scale to B (cols of B == cols of C)
        P[0] *= sc; P[1] *= sc; P[2] *= sc; P[3] *= sc;
        bfrag = pack_bf16x4(P[0], P[1], P[2], P[3]);

        float es[8];
#pragma unroll
        for (int r = 0; r < 8; ++r) es[r] = __expf(hcur[r]);
        // prefetch 2 sub-blocks ahead (clamped inside the chunk)
#pragma unroll
        for (int r = 0; r < 8; ++r) {
            int tt = base + 16 + r; tt = tt > CL - 1 ? CL - 1 : tt;
            hnx2[r] = hcs[(size_t)tt * K];
        }
#pragma unroll
        for (int r = 0; r < 8; ++r) {
            if (r >= n) break;                 // wave-uniform
            s16x4 afrag = pack_bf16x4(es[r] * E0[0], es[r] * E0[1],
                                      es[r] * E0[2], es[r] * E0[3]);
            f32x4 C = __builtin_amdgcn_mfma_f32_16x16x16bf16_1k(
                afrag, bfrag, (f32x4){0.f, 0.f, 0.f, 0.f}, 0, 0, 0);
            if (r == 5) {                      // per-column max -> pending 2^e
                float m4 = fmaxf(fmaxf(C[0], C[1]), fmaxf(C[2], C[3]));
                m4 = fmaxf(m4, __shfl_xor(m4, 16, 64));
                m4 = fmaxf(m4, __shfl_xor(m4, 32, 64));
                int e = (int)(__float_as_uint(m4) >> 23) - 127;
                pend = e < -126 ? -126 : (e > 126 ? 126 : e);
            }
            bfrag = pack_bf16x4(C[0], C[1], C[2], C[3]);
            P = C;
        }
#pragma unroll
        for (int r = 0; r < 8; ++r) { hcur[r] = hnx1[r]; hnx1[r] = hnx2[r]; }
    }

    // publish chunk result to LDS
#pragma unroll
    for (int r = 0; r < 4; ++r)
        Pl[c][4 * q + r][s] = P[r];
    if (q == 0) El[c][s] = (float)esum;
    __syncthreads();

    // ---- combine (wave 0): alpha = e_START; alpha' = P~ * ldexp(w) ----
    if (c == 0) {
        int j = s;
        f32x4 Prow[NCH], Er[NCH];
#pragma unroll
        for (int cc = 0; cc < NCH; ++cc) {
#pragma unroll
            for (int r = 0; r < 4; ++r) {
                Prow[cc][r] = Pl[cc][j][4 * q + r];
                Er[cc][r]   = El[cc][4 * q + r];
            }
        }
        float Estop[4];
#pragma unroll
        for (int r = 0; r < 4; ++r)
            Estop[r] = __expf(trans[STOP_ID * K + 4 * q + r]);

        float ap[4];
#pragma unroll
        for (int r = 0; r < 4; ++r) ap[r] = (4 * q + r == START_ID) ? 1.0f : 0.0f;
        float ls = 0.f;

#pragma unroll
        for (int cc = 0; cc < NCH; ++cc) {
            float me = fmaxf(fmaxf(Er[cc][0], Er[cc][1]), fmaxf(Er[cc][2], Er[cc][3]));
            me = fmaxf(me, __shfl_xor(me, 16, 64));
            me = fmaxf(me, __shfl_xor(me, 32, 64));
            float w0 = ldexpf(ap[0], (int)(Er[cc][0] - me));
            float w1 = ldexpf(ap[1], (int)(Er[cc][1] - me));
            float w2 = ldexpf(ap[2], (int)(Er[cc][2] - me));
            float w3 = ldexpf(ap[3], (int)(Er[cc][3] - me));
            float acc = Prow[cc][0]*w0 + Prow[cc][1]*w1
                      + Prow[cc][2]*w2 + Prow[cc][3]*w3;
            acc += __shfl_xor(acc, 16, 64);
            acc += __shfl_xor(acc, 32, 64);    // alpha'[j] at every lane
            float mj = acc;
#pragma unroll
            for (int off = 1; off < 16; off <<= 1)
                mj = fmaxf(mj, __shfl_xor(mj, off, 64));
            ls += me * LN2 + __logf(mj);
            float an = acc * (1.0f / mj);
#pragma unroll
            for (int r = 0; r < 4; ++r)
                ap[r] = __shfl(an, q * 4 + r, 16);
        }

        float part = ap[0]*Estop[0] + ap[1]*Estop[1]
                   + ap[2]*Estop[2] + ap[3]*Estop[3];
        part += __shfl_xor(part, 16, 64);
        part += __shfl_xor(part, 32, 64);
        if (lane == 0)
            res[b] = ls + __logf(part) - (Gl[0] + Gl[1] + Gl[2] + Gl[3]);
    }
}

// ---------------------------------------------------------------------------
// K2: one block reduces 1024 per-sequence (fwd - gold) values, publishes mean.
// ---------------------------------------------------------------------------
__global__ __launch_bounds__(256) void crf_final(
    const float* __restrict__ res, float* __restrict__ out)
{
    int t = threadIdx.x;
    float v = 0.f;
#pragma unroll
    for (int k2 = 0; k2 < 4; ++k2) v += res[t + 256 * k2];
#pragma unroll
    for (int off = 32; off; off >>= 1) v += __shfl_xor(v, off, 64);
    __shared__ float red[4];
    if ((t & 63) == 0) red[t >> 6] = v;
    __syncthreads();
    if (t == 0) out[0] = (red[0] + red[1] + red[2] + red[3]) * (1.0f / Bn);
}

extern "C" void kernel_launch(void* const* d_in, const int* in_sizes, int n_in,
                              void* d_out, int out_size, void* d_ws, size_t ws_size,
                              hipStream_t stream)
{
    const float* h     = (const float*)d_in[0];
    const int*   y     = (const int*)d_in[1];
    const float* trans = (const float*)d_in[3];
    float* out = (float*)d_out;
    float* res = (float*)d_ws;          // 1024 floats

    crf_all<<<Bn, 256, 0, stream>>>(h, y, trans, res);
    crf_final<<<1, 256, 0, stream>>>(res, out);
}